// Round 2
// baseline (1088.868 us; speedup 1.0000x reference)
//
#include <hip/hip_runtime.h>
#include <stdint.h>

// GNN: 2-layer GCN + skip + classifier head. All fp32; edge_index int32.
// N=100000, E=1600000, F=H=128, OUT=40.
//
//   h = A_in @ W (fp32)        [gemm128]
//   out[i] = relu(dinv[i] * sum_{j in N(i)} dinv[j]*h[j] + b) (+ skip)  [aggregate]
//   final = (out1 + out2) @ Wc + bc                           [final]
//
// CSR (grouped by dst, self-loops appended) rebuilt every call -> graph-capture safe.

#define HID 128
#define OUTD 40

// ---------------- CSR build ----------------

__global__ void gnn_count_k(const int* __restrict__ edges, int* __restrict__ cnt, int E) {
    int t = blockIdx.x * 256 + threadIdx.x;
    if (t < E) atomicAdd(&cnt[edges[E + t]], 1);
}

// block-level inclusive scan of (cnt[i]+1)  (+1 = self loop)
__global__ void gnn_scan_block_k(const int* __restrict__ cnt, int* __restrict__ scanbuf,
                                 int* __restrict__ bsum, int n) {
    __shared__ int s[256];
    int i = blockIdx.x * 256 + threadIdx.x;
    int v = (i < n) ? (cnt[i] + 1) : 0;
    s[threadIdx.x] = v;
    __syncthreads();
    for (int off = 1; off < 256; off <<= 1) {
        int t = 0;
        if (threadIdx.x >= off) t = s[threadIdx.x - off];
        __syncthreads();
        if (threadIdx.x >= off) s[threadIdx.x] += t;
        __syncthreads();
    }
    if (i < n) scanbuf[i] = s[threadIdx.x];
    if (threadIdx.x == 255) bsum[blockIdx.x] = s[255];
}

// single-block inclusive scan of block sums (nb <= 512)
__global__ void gnn_scan_bsum_k(int* __restrict__ bsum, int nb) {
    __shared__ int s[512];
    int v = (threadIdx.x < nb) ? bsum[threadIdx.x] : 0;
    s[threadIdx.x] = v;
    __syncthreads();
    for (int off = 1; off < 512; off <<= 1) {
        int t = 0;
        if (threadIdx.x >= off) t = s[threadIdx.x - off];
        __syncthreads();
        if (threadIdx.x >= off) s[threadIdx.x] += t;
        __syncthreads();
    }
    if (threadIdx.x < nb) bsum[threadIdx.x] = s[threadIdx.x];
}

__global__ void gnn_write_rowptr_k(const int* __restrict__ scanbuf, const int* __restrict__ bsum,
                                   int* __restrict__ rowptr, int n) {
    int i = blockIdx.x * 256 + threadIdx.x;
    if (i == 0) rowptr[0] = 0;
    if (i < n) {
        int blk = i >> 8;
        int off = (blk > 0) ? bsum[blk - 1] : 0;
        rowptr[i + 1] = scanbuf[i] + off;
    }
}

__global__ void gnn_fill_csr_k(const int* __restrict__ edges, int* __restrict__ cursor,
                               const int* __restrict__ rowptr, int* __restrict__ colidx,
                               int E, int n) {
    int t = blockIdx.x * 256 + threadIdx.x;
    if (t < E) {
        int src = edges[t];
        int dst = edges[E + t];
        int pos = atomicAdd(&cursor[dst], 1);
        colidx[rowptr[dst] + pos] = src;
    } else if (t < E + n) {
        int i = t - E;
        int pos = atomicAdd(&cursor[i], 1);
        colidx[rowptr[i] + pos] = i;  // self loop
    }
}

__global__ void gnn_dinv_k(const int* __restrict__ rowptr, float* __restrict__ dinv, int n) {
    int i = blockIdx.x * 256 + threadIdx.x;
    if (i < n) {
        int d = rowptr[i + 1] - rowptr[i];  // >= 1 (self loop)
        dinv[i] = rsqrtf((float)d);
    }
}

// ---------------- GEMM [n,128] @ [128,128] -> fp32 ----------------
// block = 256 threads = 2 rows x 128 cols; A row staged in LDS (broadcast reads);
// W is L1/L2-resident (64 KB), coalesced dword loads per k.

__global__ void gnn_gemm128_k(const float* __restrict__ A, const float* __restrict__ W,
                              float* __restrict__ out, int n) {
    __shared__ float a[2][HID];
    int sub = threadIdx.x >> 7;           // which of 2 rows
    int col = threadIdx.x & 127;
    int row = blockIdx.x * 2 + sub;
    if (row < n) a[sub][col] = A[(size_t)row * HID + col];
    __syncthreads();
    if (row >= n) return;
    const float* ar = a[sub];
    float acc = 0.0f;
#pragma unroll 8
    for (int k = 0; k < HID; ++k) acc += ar[k] * W[k * HID + col];
    out[(size_t)row * HID + col] = acc;
}

// ---------------- aggregation: one wave per node ----------------
// out[i] = relu( dinv[i] * sum_{j in N(i)} dinv[j]*h[j] + b ) [+ skip[i]]
// skip==nullptr for layer 1; layer 2 passes skip=out1 and writes out1 in place
// (each element read+written only by its own thread; gather reads h, a different buffer).

__global__ void gnn_aggregate_k(const float* __restrict__ h, const int* __restrict__ rowptr,
                                const int* __restrict__ colidx, const float* __restrict__ dinv,
                                const float* __restrict__ bias, const float* __restrict__ skip,
                                float* __restrict__ out, int n) {
    int node = blockIdx.x * 4 + (threadIdx.x >> 6);
    if (node >= n) return;
    int lane = threadIdx.x & 63;
    int c0 = lane * 2;
    int beg = rowptr[node];
    int end = rowptr[node + 1];
    float acc0 = 0.0f, acc1 = 0.0f;
    for (int e = beg; e < end; ++e) {
        int j = colidx[e];
        float w = dinv[j];
        float2 hv = *(const float2*)(h + (size_t)j * HID + c0);
        acc0 += w * hv.x;
        acc1 += w * hv.y;
    }
    float di = dinv[node];
    float o0 = fmaxf(di * acc0 + bias[c0], 0.0f);
    float o1 = fmaxf(di * acc1 + bias[c0 + 1], 0.0f);
    if (skip) {
        o0 += skip[(size_t)node * HID + c0];
        o1 += skip[(size_t)node * HID + c0 + 1];
    }
    out[(size_t)node * HID + c0]     = o0;
    out[(size_t)node * HID + c0 + 1] = o1;
}

// ---------------- final: sum[n,128] @ Wc[128,40] + bc -> fp32 ----------------
// block = 256 threads, 6 rows/block, 40 cols (240 active compute lanes)

__global__ void gnn_final_k(const float* __restrict__ sum, const float* __restrict__ wc,
                            const float* __restrict__ bc, float* __restrict__ out, int n) {
    const int RPB = 6;
    __shared__ float s[RPB * HID];
    int row0 = blockIdx.x * RPB;
    for (int e = threadIdx.x; e < RPB * HID; e += 256) {
        int r = row0 + e / HID;
        float v = 0.0f;
        if (r < n) v = sum[(size_t)r * HID + (e & (HID - 1))];
        s[e] = v;
    }
    __syncthreads();
    int t = threadIdx.x;
    if (t < RPB * OUTD) {
        int r = t / OUTD;
        int c = t - r * OUTD;
        int row = row0 + r;
        if (row < n) {
            const float* sr = s + r * HID;
            float acc = bc[c];
#pragma unroll 8
            for (int k = 0; k < HID; ++k) acc += sr[k] * wc[k * OUTD + c];
            out[(size_t)row * OUTD + c] = acc;
        }
    }
}

// ---------------- launch ----------------

extern "C" void kernel_launch(void* const* d_in, const int* in_sizes, int n_in,
                              void* d_out, int out_size, void* d_ws, size_t ws_size,
                              hipStream_t stream) {
    const int N = in_sizes[0] / HID;   // 100000
    const int E = in_sizes[7] / 2;     // 1600000

    const float* x  = (const float*)d_in[0];
    const float* W1 = (const float*)d_in[1];
    const float* b1 = (const float*)d_in[2];
    const float* W2 = (const float*)d_in[3];
    const float* b2 = (const float*)d_in[4];
    const float* Wc = (const float*)d_in[5];
    const float* bc = (const float*)d_in[6];
    const int* edges = (const int*)d_in[7];
    float* out = (float*)d_out;

    // workspace carve-up (256B aligned) — ~110 MB total
    char* w = (char*)d_ws;
    auto alloc = [&](size_t bytes) -> char* {
        char* p = w;
        w += (bytes + 255) & ~(size_t)255;
        return p;
    };
    float* bufA    = (float*)alloc((size_t)N * HID * 4);  // h (both layers)
    float* bufB    = (float*)alloc((size_t)N * HID * 4);  // out1, then out1+out2
    int*   cnt     = (int*)alloc((size_t)N * 4);
    int*   cursor  = (int*)alloc((size_t)N * 4);
    int*   rowptr  = (int*)alloc((size_t)(N + 1) * 4);
    int*   scanbuf = (int*)alloc((size_t)N * 4);
    int*   bsum    = (int*)alloc(512 * 4);
    int*   colidx  = (int*)alloc((size_t)(E + N) * 4);
    float* dinv    = (float*)alloc((size_t)N * 4);

    const int nb1 = (N + 255) / 256;  // 391 <= 512

    hipMemsetAsync(cnt, 0, (size_t)N * 4, stream);
    hipMemsetAsync(cursor, 0, (size_t)N * 4, stream);

    gnn_count_k<<<(E + 255) / 256, 256, 0, stream>>>(edges, cnt, E);
    gnn_scan_block_k<<<nb1, 256, 0, stream>>>(cnt, scanbuf, bsum, N);
    gnn_scan_bsum_k<<<1, 512, 0, stream>>>(bsum, nb1);
    gnn_write_rowptr_k<<<nb1, 256, 0, stream>>>(scanbuf, bsum, rowptr, N);
    gnn_fill_csr_k<<<(E + N + 255) / 256, 256, 0, stream>>>(edges, cursor, rowptr, colidx, E, N);
    gnn_dinv_k<<<nb1, 256, 0, stream>>>(rowptr, dinv, N);

    // layer 1: h1 = x @ W1 ; out1 = relu(agg(h1) + b1)
    gnn_gemm128_k<<<(N + 1) / 2, 256, 0, stream>>>(x, W1, bufA, N);
    gnn_aggregate_k<<<(N + 3) / 4, 256, 0, stream>>>(bufA, rowptr, colidx, dinv, b1, nullptr, bufB, N);
    // layer 2: h2 = out1 @ W2 ; bufB = relu(agg(h2) + b2) + out1   (in place)
    gnn_gemm128_k<<<(N + 1) / 2, 256, 0, stream>>>(bufB, W2, bufA, N);
    gnn_aggregate_k<<<(N + 3) / 4, 256, 0, stream>>>(bufA, rowptr, colidx, dinv, b2, bufB, bufB, N);
    // head: out = bufB @ Wc + bc
    gnn_final_k<<<(N + 5) / 6, 256, 0, stream>>>(bufB, Wc, bc, out, N);
}

// Round 3
// 783.781 us; speedup vs baseline: 1.3893x; 1.3893x over previous
//
#include <hip/hip_runtime.h>
#include <stdint.h>

// GNN: 2-layer GCN + skip + classifier head. All fp32; edge_index int32.
// N=100000, E=1600000, F=H=128, OUT=40.
//
//   h = A_in @ W (fp32)        [gemm128: 32x128 tile, 4x4 regs/thread]
//   out[i] = relu(dinv[i] * sum_{j in N(i)} dinv[j]*h[j] + b) (+ skip)  [aggregate]
//   final = (out1 + out2) @ Wc + bc   [final: 64x40 tile, 2x4 regs/thread]
//
// CSR (grouped by dst, self-loops appended) rebuilt every call -> graph-capture safe.

#define HID 128
#define OUTD 40

// ---------------- CSR build ----------------

__global__ void gnn_count_k(const int* __restrict__ edges, int* __restrict__ cnt, int E) {
    int t = blockIdx.x * 256 + threadIdx.x;
    if (t < E) atomicAdd(&cnt[edges[E + t]], 1);
}

// block-level inclusive scan of (cnt[i]+1)  (+1 = self loop)
__global__ void gnn_scan_block_k(const int* __restrict__ cnt, int* __restrict__ scanbuf,
                                 int* __restrict__ bsum, int n) {
    __shared__ int s[256];
    int i = blockIdx.x * 256 + threadIdx.x;
    int v = (i < n) ? (cnt[i] + 1) : 0;
    s[threadIdx.x] = v;
    __syncthreads();
    for (int off = 1; off < 256; off <<= 1) {
        int t = 0;
        if (threadIdx.x >= off) t = s[threadIdx.x - off];
        __syncthreads();
        if (threadIdx.x >= off) s[threadIdx.x] += t;
        __syncthreads();
    }
    if (i < n) scanbuf[i] = s[threadIdx.x];
    if (threadIdx.x == 255) bsum[blockIdx.x] = s[255];
}

// single-block inclusive scan of block sums (nb <= 512)
__global__ void gnn_scan_bsum_k(int* __restrict__ bsum, int nb) {
    __shared__ int s[512];
    int v = (threadIdx.x < nb) ? bsum[threadIdx.x] : 0;
    s[threadIdx.x] = v;
    __syncthreads();
    for (int off = 1; off < 512; off <<= 1) {
        int t = 0;
        if (threadIdx.x >= off) t = s[threadIdx.x - off];
        __syncthreads();
        if (threadIdx.x >= off) s[threadIdx.x] += t;
        __syncthreads();
    }
    if (threadIdx.x < nb) bsum[threadIdx.x] = s[threadIdx.x];
}

__global__ void gnn_write_rowptr_k(const int* __restrict__ scanbuf, const int* __restrict__ bsum,
                                   int* __restrict__ rowptr, int n) {
    int i = blockIdx.x * 256 + threadIdx.x;
    if (i == 0) rowptr[0] = 0;
    if (i < n) {
        int blk = i >> 8;
        int off = (blk > 0) ? bsum[blk - 1] : 0;
        rowptr[i + 1] = scanbuf[i] + off;
    }
}

__global__ void gnn_fill_csr_k(const int* __restrict__ edges, int* __restrict__ cursor,
                               const int* __restrict__ rowptr, int* __restrict__ colidx,
                               int E, int n) {
    int t = blockIdx.x * 256 + threadIdx.x;
    if (t < E) {
        int src = edges[t];
        int dst = edges[E + t];
        int pos = atomicAdd(&cursor[dst], 1);
        colidx[rowptr[dst] + pos] = src;
    } else if (t < E + n) {
        int i = t - E;
        int pos = atomicAdd(&cursor[i], 1);
        colidx[rowptr[i] + pos] = i;  // self loop
    }
}

__global__ void gnn_dinv_k(const int* __restrict__ rowptr, float* __restrict__ dinv, int n) {
    int i = blockIdx.x * 256 + threadIdx.x;
    if (i < n) {
        int d = rowptr[i + 1] - rowptr[i];  // >= 1 (self loop)
        dinv[i] = rsqrtf((float)d);
    }
}

// ---------------- GEMM [n,128] @ [128,128] -> fp32 ----------------
// 32 rows x 128 cols per block; 256 threads; each thread 4 rows x 4 cols.
// Per k-quad: 4x ds_read_b128 (2-way bank alias only = free) + 4x global float4 W
// + 64 FMA -> FMA-bound.

__global__ __launch_bounds__(256) void gnn_gemm128_k(const float* __restrict__ A,
                                                     const float* __restrict__ W,
                                                     float* __restrict__ out, int n) {
    __shared__ float a[32][HID];  // 16 KB
    const int tx = threadIdx.x & 31;   // col4 group: cols tx*4..tx*4+3
    const int ty = threadIdx.x >> 5;   // rows ty*4..ty*4+3
    const int row0 = blockIdx.x * 32;

    // stage A tile (coalesced float4)
    {
        const float4* A4 = (const float4*)A;
        float4* s4 = (float4*)&a[0][0];
#pragma unroll
        for (int i = 0; i < 4; ++i) {
            int idx = threadIdx.x + i * 256;   // 0..1023
            int r = idx >> 5, c = idx & 31;
            float4 v = make_float4(0.f, 0.f, 0.f, 0.f);
            if (row0 + r < n) v = A4[(size_t)(row0 + r) * 32 + c];
            s4[idx] = v;
        }
    }
    __syncthreads();

    float acc[4][4] = {};   // [row][col]
    const float* wp = W + tx * 4;

#pragma unroll 2
    for (int k = 0; k < HID; k += 4) {
        float ar[4][4];
#pragma unroll
        for (int r = 0; r < 4; ++r)
            *(float4*)&ar[r][0] = *(const float4*)&a[ty * 4 + r][k];
#pragma unroll
        for (int kk = 0; kk < 4; ++kk) {
            float4 w = *(const float4*)(wp + (size_t)(k + kk) * HID);
#pragma unroll
            for (int r = 0; r < 4; ++r) {
                acc[r][0] += ar[r][kk] * w.x;
                acc[r][1] += ar[r][kk] * w.y;
                acc[r][2] += ar[r][kk] * w.z;
                acc[r][3] += ar[r][kk] * w.w;
            }
        }
    }

#pragma unroll
    for (int r = 0; r < 4; ++r) {
        int row = row0 + ty * 4 + r;
        if (row < n) {
            float4 v = make_float4(acc[r][0], acc[r][1], acc[r][2], acc[r][3]);
            *(float4*)(out + (size_t)row * HID + tx * 4) = v;
        }
    }
}

// ---------------- aggregation: one wave per node ----------------
// out[i] = relu( dinv[i] * sum_{j in N(i)} dinv[j]*h[j] + b ) [+ skip[i]]
// skip==nullptr for layer 1; layer 2 passes skip=out1 and writes out1 in place
// (each element read+written only by its own thread; gather reads h, a different buffer).

__global__ void gnn_aggregate_k(const float* __restrict__ h, const int* __restrict__ rowptr,
                                const int* __restrict__ colidx, const float* __restrict__ dinv,
                                const float* __restrict__ bias, const float* __restrict__ skip,
                                float* __restrict__ out, int n) {
    int node = blockIdx.x * 4 + (threadIdx.x >> 6);
    if (node >= n) return;
    int lane = threadIdx.x & 63;
    int c0 = lane * 2;
    int beg = rowptr[node];
    int end = rowptr[node + 1];
    float acc0 = 0.0f, acc1 = 0.0f;
    for (int e = beg; e < end; ++e) {
        int j = colidx[e];
        float w = dinv[j];
        float2 hv = *(const float2*)(h + (size_t)j * HID + c0);
        acc0 += w * hv.x;
        acc1 += w * hv.y;
    }
    float di = dinv[node];
    float o0 = fmaxf(di * acc0 + bias[c0], 0.0f);
    float o1 = fmaxf(di * acc1 + bias[c0 + 1], 0.0f);
    if (skip) {
        o0 += skip[(size_t)node * HID + c0];
        o1 += skip[(size_t)node * HID + c0 + 1];
    }
    out[(size_t)node * HID + c0]     = o0;
    out[(size_t)node * HID + c0 + 1] = o1;
}

// ---------------- final: sum[n,128] @ Wc[128,40] + bc -> fp32 ----------------
// 64 rows x 40 cols per block; 320 threads (tx=tid%10 col4-group, ty=tid/10 row pair);
// each thread 2 rows x 4 cols. A staged in LDS with XOR-swizzled float4 blocks
// (reads hit distinct rows at the same k-block -> swizzle spreads banks).
// Wc (20 KB) streamed from L1.

__global__ __launch_bounds__(320) void gnn_final_k(const float* __restrict__ sum,
                                                   const float* __restrict__ wc,
                                                   const float* __restrict__ bc,
                                                   float* __restrict__ out, int n) {
    __shared__ float a[64 * HID];  // 32 KB, float4 block (r, c4) stored at r*32 + (c4 ^ (r&7))
    const int tx = threadIdx.x % 10;   // cols tx*4..tx*4+3
    const int ty = threadIdx.x / 10;   // rows ty*2, ty*2+1
    const int row0 = blockIdx.x * 64;

    {
        const float4* S4 = (const float4*)sum;
        float4* s4 = (float4*)a;
        for (int idx = threadIdx.x; idx < 64 * 32; idx += 320) {
            int r = idx >> 5, c = idx & 31;
            float4 v = make_float4(0.f, 0.f, 0.f, 0.f);
            if (row0 + r < n) v = S4[(size_t)(row0 + r) * 32 + c];
            s4[r * 32 + (c ^ (r & 7))] = v;
        }
    }
    __syncthreads();

    float acc[2][4];
    {
        float b0 = bc[tx * 4], b1 = bc[tx * 4 + 1], b2 = bc[tx * 4 + 2], b3 = bc[tx * 4 + 3];
        acc[0][0] = b0; acc[0][1] = b1; acc[0][2] = b2; acc[0][3] = b3;
        acc[1][0] = b0; acc[1][1] = b1; acc[1][2] = b2; acc[1][3] = b3;
    }
    const float* wp = wc + tx * 4;
    const float4* s4 = (const float4*)a;

#pragma unroll 2
    for (int k = 0; k < HID; k += 4) {
        int c4 = k >> 2;
        float ar[2][4];
#pragma unroll
        for (int r = 0; r < 2; ++r) {
            int row = ty * 2 + r;
            *(float4*)&ar[r][0] = s4[row * 32 + (c4 ^ (row & 7))];
        }
#pragma unroll
        for (int kk = 0; kk < 4; ++kk) {
            float4 w = *(const float4*)(wp + (size_t)(k + kk) * OUTD);
#pragma unroll
            for (int r = 0; r < 2; ++r) {
                acc[r][0] += ar[r][kk] * w.x;
                acc[r][1] += ar[r][kk] * w.y;
                acc[r][2] += ar[r][kk] * w.z;
                acc[r][3] += ar[r][kk] * w.w;
            }
        }
    }

#pragma unroll
    for (int r = 0; r < 2; ++r) {
        int row = row0 + ty * 2 + r;
        if (row < n) {
            float4 v = make_float4(acc[r][0], acc[r][1], acc[r][2], acc[r][3]);
            *(float4*)(out + (size_t)row * OUTD + tx * 4) = v;
        }
    }
}

// ---------------- launch ----------------

extern "C" void kernel_launch(void* const* d_in, const int* in_sizes, int n_in,
                              void* d_out, int out_size, void* d_ws, size_t ws_size,
                              hipStream_t stream) {
    const int N = in_sizes[0] / HID;   // 100000
    const int E = in_sizes[7] / 2;     // 1600000

    const float* x  = (const float*)d_in[0];
    const float* W1 = (const float*)d_in[1];
    const float* b1 = (const float*)d_in[2];
    const float* W2 = (const float*)d_in[3];
    const float* b2 = (const float*)d_in[4];
    const float* Wc = (const float*)d_in[5];
    const float* bc = (const float*)d_in[6];
    const int* edges = (const int*)d_in[7];
    float* out = (float*)d_out;

    // workspace carve-up (256B aligned) — ~110 MB total
    char* w = (char*)d_ws;
    auto alloc = [&](size_t bytes) -> char* {
        char* p = w;
        w += (bytes + 255) & ~(size_t)255;
        return p;
    };
    float* bufA    = (float*)alloc((size_t)N * HID * 4);  // h (both layers)
    float* bufB    = (float*)alloc((size_t)N * HID * 4);  // out1, then out1+out2
    int*   cnt     = (int*)alloc((size_t)N * 4);
    int*   cursor  = (int*)alloc((size_t)N * 4);
    int*   rowptr  = (int*)alloc((size_t)(N + 1) * 4);
    int*   scanbuf = (int*)alloc((size_t)N * 4);
    int*   bsum    = (int*)alloc(512 * 4);
    int*   colidx  = (int*)alloc((size_t)(E + N) * 4);
    float* dinv    = (float*)alloc((size_t)N * 4);

    const int nb1 = (N + 255) / 256;  // 391 <= 512

    hipMemsetAsync(cnt, 0, (size_t)N * 4, stream);
    hipMemsetAsync(cursor, 0, (size_t)N * 4, stream);

    gnn_count_k<<<(E + 255) / 256, 256, 0, stream>>>(edges, cnt, E);
    gnn_scan_block_k<<<nb1, 256, 0, stream>>>(cnt, scanbuf, bsum, N);
    gnn_scan_bsum_k<<<1, 512, 0, stream>>>(bsum, nb1);
    gnn_write_rowptr_k<<<nb1, 256, 0, stream>>>(scanbuf, bsum, rowptr, N);
    gnn_fill_csr_k<<<(E + N + 255) / 256, 256, 0, stream>>>(edges, cursor, rowptr, colidx, E, N);
    gnn_dinv_k<<<nb1, 256, 0, stream>>>(rowptr, dinv, N);

    // layer 1: h1 = x @ W1 ; out1 = relu(agg(h1) + b1)
    gnn_gemm128_k<<<(N + 31) / 32, 256, 0, stream>>>(x, W1, bufA, N);
    gnn_aggregate_k<<<(N + 3) / 4, 256, 0, stream>>>(bufA, rowptr, colidx, dinv, b1, nullptr, bufB, N);
    // layer 2: h2 = out1 @ W2 ; bufB = relu(agg(h2) + b2) + out1   (in place)
    gnn_gemm128_k<<<(N + 31) / 32, 256, 0, stream>>>(bufB, W2, bufA, N);
    gnn_aggregate_k<<<(N + 3) / 4, 256, 0, stream>>>(bufA, rowptr, colidx, dinv, b2, bufB, bufB, N);
    // head: out = bufB @ Wc + bc
    gnn_final_k<<<(N + 63) / 64, 320, 0, stream>>>(bufB, Wc, bc, out, N);
}

// Round 4
// 664.193 us; speedup vs baseline: 1.6394x; 1.1800x over previous
//
#include <hip/hip_runtime.h>
#include <stdint.h>

// GNN: 2-layer GCN + skip + classifier head. All fp32 in/out; edge_index int32.
// N=100000, E=1600000, F=H=128, OUT=40.
//
//   h = A_in @ W  -> stored BF16 (halves the random-gather bytes; fp32 accum everywhere)
//   out[i] = relu(dinv[i] * sum_{j in N(i)} dinv[j]*h[j] + b) (+ skip)  [aggregate]
//   final = (out1 + out2) @ Wc + bc   (fp32)
//
// CSR (grouped by dst, self-loops appended) rebuilt every call -> graph-capture safe.

#define HID 128
#define OUTD 40

// bf16 helpers (RNE pack, exact unpack)
__device__ inline uint16_t f32_to_bf16(float f) {
    uint32_t u = __float_as_uint(f);
    uint32_t r = u + 0x7FFFu + ((u >> 16) & 1u);
    return (uint16_t)(r >> 16);
}

// ---------------- CSR build ----------------

__global__ void gnn_count_k(const int* __restrict__ edges, int* __restrict__ cnt, int E) {
    int t = blockIdx.x * 256 + threadIdx.x;
    if (t < E) atomicAdd(&cnt[edges[E + t]], 1);
}

// block-level inclusive scan of (cnt[i]+1)  (+1 = self loop)
__global__ void gnn_scan_block_k(const int* __restrict__ cnt, int* __restrict__ scanbuf,
                                 int* __restrict__ bsum, int n) {
    __shared__ int s[256];
    int i = blockIdx.x * 256 + threadIdx.x;
    int v = (i < n) ? (cnt[i] + 1) : 0;
    s[threadIdx.x] = v;
    __syncthreads();
    for (int off = 1; off < 256; off <<= 1) {
        int t = 0;
        if (threadIdx.x >= off) t = s[threadIdx.x - off];
        __syncthreads();
        if (threadIdx.x >= off) s[threadIdx.x] += t;
        __syncthreads();
    }
    if (i < n) scanbuf[i] = s[threadIdx.x];
    if (threadIdx.x == 255) bsum[blockIdx.x] = s[255];
}

// single-block inclusive scan of block sums (nb <= 512)
__global__ void gnn_scan_bsum_k(int* __restrict__ bsum, int nb) {
    __shared__ int s[512];
    int v = (threadIdx.x < nb) ? bsum[threadIdx.x] : 0;
    s[threadIdx.x] = v;
    __syncthreads();
    for (int off = 1; off < 512; off <<= 1) {
        int t = 0;
        if (threadIdx.x >= off) t = s[threadIdx.x - off];
        __syncthreads();
        if (threadIdx.x >= off) s[threadIdx.x] += t;
        __syncthreads();
    }
    if (threadIdx.x < nb) bsum[threadIdx.x] = s[threadIdx.x];
}

__global__ void gnn_write_rowptr_k(const int* __restrict__ scanbuf, const int* __restrict__ bsum,
                                   int* __restrict__ rowptr, int n) {
    int i = blockIdx.x * 256 + threadIdx.x;
    if (i == 0) rowptr[0] = 0;
    if (i < n) {
        int blk = i >> 8;
        int off = (blk > 0) ? bsum[blk - 1] : 0;
        rowptr[i + 1] = scanbuf[i] + off;
    }
}

__global__ void gnn_fill_csr_k(const int* __restrict__ edges, int* __restrict__ cursor,
                               const int* __restrict__ rowptr, int* __restrict__ colidx,
                               int E, int n) {
    int t = blockIdx.x * 256 + threadIdx.x;
    if (t < E) {
        int src = edges[t];
        int dst = edges[E + t];
        int pos = atomicAdd(&cursor[dst], 1);
        colidx[rowptr[dst] + pos] = src;
    } else if (t < E + n) {
        int i = t - E;
        int pos = atomicAdd(&cursor[i], 1);
        colidx[rowptr[i] + pos] = i;  // self loop
    }
}

__global__ void gnn_dinv_k(const int* __restrict__ rowptr, float* __restrict__ dinv, int n) {
    int i = blockIdx.x * 256 + threadIdx.x;
    if (i < n) {
        int d = rowptr[i + 1] - rowptr[i];  // >= 1 (self loop)
        dinv[i] = rsqrtf((float)d);
    }
}

// ---------------- GEMM [n,128] @ [128,128] -> bf16 h ----------------
// 32 rows x 128 cols per block; 256 threads; each thread 4 rows x 4 cols.
// Per k-quad: 4x ds_read_b128 + 4x global float4 W + 64 FMA -> FMA-bound.
// Output packed bf16 (RNE) -> halves the aggregate gather bytes.

__global__ __launch_bounds__(256) void gnn_gemm128_k(const float* __restrict__ A,
                                                     const float* __restrict__ W,
                                                     uint16_t* __restrict__ outh, int n) {
    __shared__ float a[32][HID];  // 16 KB
    const int tx = threadIdx.x & 31;   // col4 group: cols tx*4..tx*4+3
    const int ty = threadIdx.x >> 5;   // rows ty*4..ty*4+3
    const int row0 = blockIdx.x * 32;

    // stage A tile (coalesced float4)
    {
        const float4* A4 = (const float4*)A;
        float4* s4 = (float4*)&a[0][0];
#pragma unroll
        for (int i = 0; i < 4; ++i) {
            int idx = threadIdx.x + i * 256;   // 0..1023
            int r = idx >> 5, c = idx & 31;
            float4 v = make_float4(0.f, 0.f, 0.f, 0.f);
            if (row0 + r < n) v = A4[(size_t)(row0 + r) * 32 + c];
            s4[idx] = v;
        }
    }
    __syncthreads();

    float acc[4][4] = {};   // [row][col]
    const float* wp = W + tx * 4;

#pragma unroll 2
    for (int k = 0; k < HID; k += 4) {
        float ar[4][4];
#pragma unroll
        for (int r = 0; r < 4; ++r)
            *(float4*)&ar[r][0] = *(const float4*)&a[ty * 4 + r][k];
#pragma unroll
        for (int kk = 0; kk < 4; ++kk) {
            float4 w = *(const float4*)(wp + (size_t)(k + kk) * HID);
#pragma unroll
            for (int r = 0; r < 4; ++r) {
                acc[r][0] += ar[r][kk] * w.x;
                acc[r][1] += ar[r][kk] * w.y;
                acc[r][2] += ar[r][kk] * w.z;
                acc[r][3] += ar[r][kk] * w.w;
            }
        }
    }

#pragma unroll
    for (int r = 0; r < 4; ++r) {
        int row = row0 + ty * 4 + r;
        if (row < n) {
            uint2 v;
            v.x = (uint32_t)f32_to_bf16(acc[r][0]) | ((uint32_t)f32_to_bf16(acc[r][1]) << 16);
            v.y = (uint32_t)f32_to_bf16(acc[r][2]) | ((uint32_t)f32_to_bf16(acc[r][3]) << 16);
            *(uint2*)((uint16_t*)outh + (size_t)row * HID + tx * 4) = v;
        }
    }
}

// ---------------- aggregation: one wave per node, bf16 h gather ----------------
// out[i] = relu( dinv[i] * sum_{j in N(i)} dinv[j]*h[j] + b ) [+ skip[i]]
// Each lane owns 2 columns -> one dword per neighbor row (256 B/row per wave,
// coalesced). 2-edge manual unroll keeps 2 fills in flight.

__global__ void gnn_aggregate_k(const uint32_t* __restrict__ h, const int* __restrict__ rowptr,
                                const int* __restrict__ colidx, const float* __restrict__ dinv,
                                const float* __restrict__ bias, const float* __restrict__ skip,
                                float* __restrict__ out, int n) {
    int node = blockIdx.x * 4 + (threadIdx.x >> 6);
    if (node >= n) return;
    int lane = threadIdx.x & 63;
    int c0 = lane * 2;
    int beg = rowptr[node];
    int end = rowptr[node + 1];
    float acc0 = 0.0f, acc1 = 0.0f;
    int e = beg;
    for (; e + 1 < end; e += 2) {
        int j0 = colidx[e];
        int j1 = colidx[e + 1];
        float w0 = dinv[j0];
        float w1 = dinv[j1];
        uint32_t u0 = h[(size_t)j0 * 64 + lane];
        uint32_t u1 = h[(size_t)j1 * 64 + lane];
        acc0 += w0 * __uint_as_float(u0 << 16);
        acc1 += w0 * __uint_as_float(u0 & 0xFFFF0000u);
        acc0 += w1 * __uint_as_float(u1 << 16);
        acc1 += w1 * __uint_as_float(u1 & 0xFFFF0000u);
    }
    if (e < end) {
        int j = colidx[e];
        float w = dinv[j];
        uint32_t u = h[(size_t)j * 64 + lane];
        acc0 += w * __uint_as_float(u << 16);
        acc1 += w * __uint_as_float(u & 0xFFFF0000u);
    }
    float di = dinv[node];
    float o0 = fmaxf(di * acc0 + bias[c0], 0.0f);
    float o1 = fmaxf(di * acc1 + bias[c0 + 1], 0.0f);
    if (skip) {
        o0 += skip[(size_t)node * HID + c0];
        o1 += skip[(size_t)node * HID + c0 + 1];
    }
    out[(size_t)node * HID + c0]     = o0;
    out[(size_t)node * HID + c0 + 1] = o1;
}

// ---------------- final: sum[n,128] @ Wc[128,40] + bc -> fp32 ----------------
// 64 rows x 40 cols per block; 320 threads; each thread 2 rows x 4 cols.
// A staged in LDS with XOR-swizzled float4 blocks.

__global__ __launch_bounds__(320) void gnn_final_k(const float* __restrict__ sum,
                                                   const float* __restrict__ wc,
                                                   const float* __restrict__ bc,
                                                   float* __restrict__ out, int n) {
    __shared__ float a[64 * HID];  // 32 KB, float4 block (r, c4) at r*32 + (c4 ^ (r&7))
    const int tx = threadIdx.x % 10;   // cols tx*4..tx*4+3
    const int ty = threadIdx.x / 10;   // rows ty*2, ty*2+1
    const int row0 = blockIdx.x * 64;

    {
        const float4* S4 = (const float4*)sum;
        float4* s4 = (float4*)a;
        for (int idx = threadIdx.x; idx < 64 * 32; idx += 320) {
            int r = idx >> 5, c = idx & 31;
            float4 v = make_float4(0.f, 0.f, 0.f, 0.f);
            if (row0 + r < n) v = S4[(size_t)(row0 + r) * 32 + c];
            s4[r * 32 + (c ^ (r & 7))] = v;
        }
    }
    __syncthreads();

    float acc[2][4];
    {
        float b0 = bc[tx * 4], b1 = bc[tx * 4 + 1], b2 = bc[tx * 4 + 2], b3 = bc[tx * 4 + 3];
        acc[0][0] = b0; acc[0][1] = b1; acc[0][2] = b2; acc[0][3] = b3;
        acc[1][0] = b0; acc[1][1] = b1; acc[1][2] = b2; acc[1][3] = b3;
    }
    const float* wp = wc + tx * 4;
    const float4* s4 = (const float4*)a;

#pragma unroll 2
    for (int k = 0; k < HID; k += 4) {
        int c4 = k >> 2;
        float ar[2][4];
#pragma unroll
        for (int r = 0; r < 2; ++r) {
            int row = ty * 2 + r;
            *(float4*)&ar[r][0] = s4[row * 32 + (c4 ^ (row & 7))];
        }
#pragma unroll
        for (int kk = 0; kk < 4; ++kk) {
            float4 w = *(const float4*)(wp + (size_t)(k + kk) * OUTD);
#pragma unroll
            for (int r = 0; r < 2; ++r) {
                acc[r][0] += ar[r][kk] * w.x;
                acc[r][1] += ar[r][kk] * w.y;
                acc[r][2] += ar[r][kk] * w.z;
                acc[r][3] += ar[r][kk] * w.w;
            }
        }
    }

#pragma unroll
    for (int r = 0; r < 2; ++r) {
        int row = row0 + ty * 2 + r;
        if (row < n) {
            float4 v = make_float4(acc[r][0], acc[r][1], acc[r][2], acc[r][3]);
            *(float4*)(out + (size_t)row * OUTD + tx * 4) = v;
        }
    }
}

// ---------------- launch ----------------

extern "C" void kernel_launch(void* const* d_in, const int* in_sizes, int n_in,
                              void* d_out, int out_size, void* d_ws, size_t ws_size,
                              hipStream_t stream) {
    const int N = in_sizes[0] / HID;   // 100000
    const int E = in_sizes[7] / 2;     // 1600000

    const float* x  = (const float*)d_in[0];
    const float* W1 = (const float*)d_in[1];
    const float* b1 = (const float*)d_in[2];
    const float* W2 = (const float*)d_in[3];
    const float* b2 = (const float*)d_in[4];
    const float* Wc = (const float*)d_in[5];
    const float* bc = (const float*)d_in[6];
    const int* edges = (const int*)d_in[7];
    float* out = (float*)d_out;

    // workspace carve-up (256B aligned)
    char* w = (char*)d_ws;
    auto alloc = [&](size_t bytes) -> char* {
        char* p = w;
        w += (bytes + 255) & ~(size_t)255;
        return p;
    };
    uint16_t* hbuf = (uint16_t*)alloc((size_t)N * HID * 2);  // h, bf16 (both layers)
    float* bufB    = (float*)alloc((size_t)N * HID * 4);     // out1, then out1+out2
    int*   cnt     = (int*)alloc((size_t)N * 4);
    int*   cursor  = (int*)alloc((size_t)N * 4);
    int*   rowptr  = (int*)alloc((size_t)(N + 1) * 4);
    int*   scanbuf = (int*)alloc((size_t)N * 4);
    int*   bsum    = (int*)alloc(512 * 4);
    int*   colidx  = (int*)alloc((size_t)(E + N) * 4);
    float* dinv    = (float*)alloc((size_t)N * 4);

    const int nb1 = (N + 255) / 256;  // 391 <= 512

    hipMemsetAsync(cnt, 0, (size_t)N * 4, stream);
    hipMemsetAsync(cursor, 0, (size_t)N * 4, stream);

    gnn_count_k<<<(E + 255) / 256, 256, 0, stream>>>(edges, cnt, E);
    gnn_scan_block_k<<<nb1, 256, 0, stream>>>(cnt, scanbuf, bsum, N);
    gnn_scan_bsum_k<<<1, 512, 0, stream>>>(bsum, nb1);
    gnn_write_rowptr_k<<<nb1, 256, 0, stream>>>(scanbuf, bsum, rowptr, N);
    gnn_fill_csr_k<<<(E + N + 255) / 256, 256, 0, stream>>>(edges, cursor, rowptr, colidx, E, N);
    gnn_dinv_k<<<nb1, 256, 0, stream>>>(rowptr, dinv, N);

    // layer 1: h1 = bf16(x @ W1) ; out1 = relu(agg(h1) + b1)
    gnn_gemm128_k<<<(N + 31) / 32, 256, 0, stream>>>(x, W1, hbuf, N);
    gnn_aggregate_k<<<(N + 3) / 4, 256, 0, stream>>>((const uint32_t*)hbuf, rowptr, colidx,
                                                     dinv, b1, nullptr, bufB, N);
    // layer 2: h2 = bf16(out1 @ W2) ; bufB = relu(agg(h2) + b2) + out1   (in place)
    gnn_gemm128_k<<<(N + 31) / 32, 256, 0, stream>>>(bufB, W2, hbuf, N);
    gnn_aggregate_k<<<(N + 3) / 4, 256, 0, stream>>>((const uint32_t*)hbuf, rowptr, colidx,
                                                     dinv, b2, bufB, bufB, N);
    // head: out = bufB @ Wc + bc
    gnn_final_k<<<(N + 63) / 64, 320, 0, stream>>>(bufB, Wc, bc, out, N);
}